// Round 1
// baseline (374.616 us; speedup 1.0000x reference)
//
#include <hip/hip_runtime.h>
#include <hip/hip_bf16.h>
#include <math.h>

#define CLASSNUM 70722
#define BATCH 512
#define EMBD 512
#define M_C 0.4f
#define H_C 0.333f
#define S_C 64.0f
#define EPS_C 0.001f
#define PI_F 3.14159265358979f

typedef __bf16 bf16_t;
typedef __bf16 bf16x8 __attribute__((ext_vector_type(8)));
typedef float f32x4 __attribute__((ext_vector_type(4)));

__device__ __forceinline__ float clampf(float x, float lo, float hi) {
    return fminf(fmaxf(x, lo), hi);
}

// ---------------------------------------------------------------------------
// prep: block 0 computes margin_scaler ms[512]; blocks 1..256 convert the
// embeddings (A) to bf16 in workspace.
// ---------------------------------------------------------------------------
__global__ __launch_bounds__(256) void prep_kernel(
    const float* __restrict__ emb, const float* __restrict__ norms,
    const float* __restrict__ csn, bf16_t* __restrict__ Aws,
    float* __restrict__ msw)
{
    __shared__ float sred[256];
    const int tid = threadIdx.x;
    if (blockIdx.x == 0) {
        float s0, s1;
        {
            float sn = clampf(norms[tid], 0.001f, 100.0f);
            sn = sn / (csn[tid] + 0.001f);
            s0 = clampf(sn, 0.001f, 100.0f);
        }
        {
            float sn = clampf(norms[tid + 256], 0.001f, 100.0f);
            sn = sn / (csn[tid + 256] + 0.001f);
            s1 = clampf(sn, 0.001f, 100.0f);
        }
        sred[tid] = s0 + s1;
        __syncthreads();
        for (int off = 128; off > 0; off >>= 1) {
            if (tid < off) sred[tid] += sred[tid + off];
            __syncthreads();
        }
        const float mean = sred[0] * (1.0f / 512.0f);
        __syncthreads();
        const float d0 = s0 - mean, d1 = s1 - mean;
        sred[tid] = d0 * d0 + d1 * d1;
        __syncthreads();
        for (int off = 128; off > 0; off >>= 1) {
            if (tid < off) sred[tid] += sred[tid + off];
            __syncthreads();
        }
        const float stdv = sqrtf(sred[0] * (1.0f / 511.0f));  // ddof=1
        const float inv = 1.0f / (stdv + EPS_C);
        msw[tid]       = clampf(d0 * inv * H_C, -1.0f, 1.0f);
        msw[tid + 256] = clampf(d1 * inv * H_C, -1.0f, 1.0f);
    } else {
        const int base = ((blockIdx.x - 1) * 256 + tid) * 4;
        const float4 v = *(const float4*)(emb + base);
        bf16_t h[4] = {(bf16_t)v.x, (bf16_t)v.y, (bf16_t)v.z, (bf16_t)v.w};
        *(unsigned long long*)(Aws + base) = *(unsigned long long*)h;
    }
}

// ---------------------------------------------------------------------------
// lab: one wave per batch row. Exact fp32 dot(emb[b], K[:,label[b]]) and the
// column norm, then the full margin formula -> labout[b]. Avoids the arccos
// error amplification the bf16 GEMM path would have near |c|~0.999.
// ---------------------------------------------------------------------------
__global__ __launch_bounds__(64) void lab_kernel(
    const float* __restrict__ emb, const int* __restrict__ label,
    const float* __restrict__ kmat, const float* __restrict__ msw,
    float* __restrict__ labout)
{
    const int b = blockIdx.x;
    const int l = threadIdx.x;
    const int lab = label[b];
    const float* col = kmat + lab;
    const float* e = emb + b * EMBD;
    float dot = 0.0f, ss = 0.0f;
    for (int k = l; k < EMBD; k += 64) {
        const float kv = col[(size_t)k * CLASSNUM];
        const float ev = e[k];
        dot = fmaf(ev, kv, dot);
        ss  = fmaf(kv, kv, ss);
    }
    for (int off = 32; off > 0; off >>= 1) {
        dot += __shfl_down(dot, off);
        ss  += __shfl_down(ss, off);
    }
    if (l == 0) {
        float c = dot / sqrtf(ss);
        c = clampf(c, -1.0f + EPS_C, 1.0f - EPS_C);
        const float msv = msw[b];
        float th = acosf(c) - M_C * msv;
        th = clampf(th, EPS_C, PI_F - EPS_C);
        labout[b] = (cosf(th) - (M_C + M_C * msv)) * S_C;
    }
}

// ---------------------------------------------------------------------------
// gemm: 128x128 tile, BK=32, 256 threads (4 waves, each 64x64 via 4x4 of
// mfma_f32_16x16x32_bf16). B (fp32) converted to bf16 during staging with
// fused per-column sum-of-squares -> inv_norm applied in the epilogue.
// LDS rows padded to 40 bf16 (80 B = 5 x 16 B granules) -> b128 accesses
// cycle all 32 banks, 2-way aliasing only (free per m136).
// ---------------------------------------------------------------------------
__global__ __launch_bounds__(256) void gemm_kernel(
    const bf16_t* __restrict__ Aws, const float* __restrict__ Kmat,
    float* __restrict__ out)
{
    __shared__ bf16_t Alds[128 * 40];
    __shared__ bf16_t Blds[128 * 40];
    __shared__ float red[256];
    __shared__ float invn[128];

    const int bid = blockIdx.x;
    const int n0 = (bid >> 2) << 7;   // consecutive bids share B slab (L3 reuse)
    const int m0 = (bid & 3) << 7;
    const int tid = threadIdx.x;
    const int lane = tid & 63;
    const int wave = tid >> 6;
    const int quad = lane >> 4;
    const int r16  = lane & 15;
    const int wm = (wave >> 1) * 64;
    const int wn = (wave & 1) * 64;

    // B staging: thread owns one column n_loc for the whole K loop.
    const int n_loc = tid & 127;
    const int which = tid >> 7;               // 0/1: k-chunk ownership
    const int n_g = n0 + n_loc;
    const bool nvalid = (n_g < CLASSNUM);
    const float* bptr = Kmat + n_g;

    // A staging: granule g in {tid, tid+256}; m = g>>2, slot = g&3.
    const int am0 = tid >> 2, as0 = tid & 3;
    const int am1 = am0 + 64;
    const bf16_t* aptr0 = Aws + (size_t)(m0 + am0) * EMBD + as0 * 8;
    const bf16_t* aptr1 = Aws + (size_t)(m0 + am1) * EMBD + as0 * 8;
    bf16_t* const awr0 = &Alds[am0 * 40 + as0 * 8];
    bf16_t* const awr1 = &Alds[am1 * 40 + as0 * 8];
    bf16_t* const bwr0 = &Blds[n_loc * 40 + which * 8];
    bf16_t* const bwr1 = &Blds[n_loc * 40 + which * 8 + 16];

    f32x4 acc[4][4];
    const f32x4 zero = {0.0f, 0.0f, 0.0f, 0.0f};
#pragma unroll
    for (int i = 0; i < 4; ++i)
#pragma unroll
        for (int j = 0; j < 4; ++j) acc[i][j] = zero;

    float ssq = 0.0f;

    for (int it = 0; it < 16; ++it) {
        const int k0 = it * 32;
        // issue all global loads first, then LDS writes
        const bf16x8 av0 = *(const bf16x8*)(aptr0 + k0);
        const bf16x8 av1 = *(const bf16x8*)(aptr1 + k0);
        float bv[16];
#pragma unroll
        for (int h = 0; h < 2; ++h) {
            const int kb = k0 + which * 8 + h * 16;
#pragma unroll
            for (int j = 0; j < 8; ++j)
                bv[h * 8 + j] = nvalid ? bptr[(size_t)(kb + j) * CLASSNUM] : 0.0f;
        }
        *(bf16x8*)awr0 = av0;
        *(bf16x8*)awr1 = av1;
#pragma unroll
        for (int h = 0; h < 2; ++h) {
            bf16x8 bw;
#pragma unroll
            for (int j = 0; j < 8; ++j) {
                const float v = bv[h * 8 + j];
                ssq = fmaf(v, v, ssq);     // fused column sum-of-squares (fp32)
                bw[j] = (bf16_t)v;
            }
            *(bf16x8*)(h ? bwr1 : bwr0) = bw;
        }
        __syncthreads();

        bf16x8 afr[4], bfr[4];
#pragma unroll
        for (int mi = 0; mi < 4; ++mi)
            afr[mi] = *(const bf16x8*)(&Alds[(wm + mi * 16 + r16) * 40 + quad * 8]);
#pragma unroll
        for (int ni = 0; ni < 4; ++ni)
            bfr[ni] = *(const bf16x8*)(&Blds[(wn + ni * 16 + r16) * 40 + quad * 8]);
#pragma unroll
        for (int mi = 0; mi < 4; ++mi)
#pragma unroll
            for (int ni = 0; ni < 4; ++ni)
                acc[mi][ni] = __builtin_amdgcn_mfma_f32_16x16x32_bf16(
                    afr[mi], bfr[ni], acc[mi][ni], 0, 0, 0);
        __syncthreads();
    }

    // reduce the 2 k-partials per column -> inv column norm
    red[tid] = ssq;
    __syncthreads();
    if (tid < 128) {
        const float s = red[tid] + red[tid + 128];
        invn[tid] = (s > 0.0f) ? (1.0f / sqrtf(s)) : 0.0f;
    }
    __syncthreads();

    // epilogue: out = S * clip(c) — cos(arccos(c)) is identity for non-label
    // entries; the 512 label entries get overwritten by scatter_kernel.
#pragma unroll
    for (int ni = 0; ni < 4; ++ni) {
        const int col_loc = wn + ni * 16 + r16;
        const int col = n0 + col_loc;
        if (col < CLASSNUM) {
            const float inv = invn[col_loc];
#pragma unroll
            for (int mi = 0; mi < 4; ++mi) {
                const int row = m0 + wm + mi * 16 + quad * 4;
                const f32x4 a = acc[mi][ni];
#pragma unroll
                for (int rr = 0; rr < 4; ++rr) {
                    const float c = clampf(a[rr] * inv, -1.0f + EPS_C, 1.0f - EPS_C);
                    out[(size_t)(row + rr) * CLASSNUM + col] = c * S_C;
                }
            }
        }
    }
}

// ---------------------------------------------------------------------------
// scatter: overwrite the 512 (row, label) entries with the exact fp32 values.
// ---------------------------------------------------------------------------
__global__ __launch_bounds__(512) void scatter_kernel(
    const int* __restrict__ label, const float* __restrict__ labout,
    float* __restrict__ out)
{
    const int t = threadIdx.x;
    out[(size_t)t * CLASSNUM + label[t]] = labout[t];
}

extern "C" void kernel_launch(void* const* d_in, const int* in_sizes, int n_in,
                              void* d_out, int out_size, void* d_ws, size_t ws_size,
                              hipStream_t stream)
{
    const float* emb   = (const float*)d_in[0];
    const float* norms = (const float*)d_in[1];
    const int*   label = (const int*)d_in[2];
    const float* csn   = (const float*)d_in[3];
    const float* kmat  = (const float*)d_in[4];
    float* out = (float*)d_out;

    // workspace layout: [A bf16 512x512 | ms 512 f32 | labout 512 f32]
    const size_t A_BYTES = (size_t)BATCH * EMBD * sizeof(bf16_t);  // 524288
    if (ws_size < A_BYTES + 4096) return;  // clean fail instead of corruption
    bf16_t* Aws   = (bf16_t*)d_ws;
    float* msw    = (float*)((char*)d_ws + A_BYTES);
    float* labout = (float*)((char*)d_ws + A_BYTES + 2048);

    prep_kernel<<<257, 256, 0, stream>>>(emb, norms, csn, Aws, msw);
    lab_kernel<<<BATCH, 64, 0, stream>>>(emb, label, kmat, msw, labout);
    const int ntiles = (CLASSNUM + 127) / 128;           // 553
    gemm_kernel<<<ntiles * 4, 256, 0, stream>>>(Aws, kmat, out);
    scatter_kernel<<<1, 512, 0, stream>>>(label, labout, out);
}